// Round 1
// baseline (525.800 us; speedup 1.0000x reference)
//
#include <hip/hip_runtime.h>
#include <cstdint>
#include <cstddef>

// ---------------------------------------------------------------------------
// GCN 2-layer + 2 linear heads, N=100000 nodes, E=1.6M edges.
// Formulation: out_i = dinv_i * ( sum_{e: dst=i} g[src_e] + g[i] ) + b,
// with g = dinv ⊙ (h @ W),  deg_i = indeg_i + 1,  dinv = rsqrt(deg).
// CSR-by-dst built once per launch, reused by both layers (pull mode, no
// float atomics). Heads fused into the layer-2 pull (h2 never materialized).
// ---------------------------------------------------------------------------

__global__ void k_deg(const int* __restrict__ dst, int* __restrict__ c, int E) {
  int e = blockIdx.x * 256 + threadIdx.x;
  if (e < E) atomicAdd(&c[dst[e]], 1);
}

__global__ void k_dinv(const int* __restrict__ c, float* __restrict__ dinv, int n) {
  int i = blockIdx.x * 256 + threadIdx.x;
  if (i < n) dinv[i] = rsqrtf((float)(c[i] + 1));
}

// --- exclusive scan of c -> rs (3-kernel: per-1024-block scan, block-sum scan, add) ---
__global__ void k_scan1(const int* __restrict__ c, int* __restrict__ rs,
                        int* __restrict__ bsum, int n) {
  __shared__ int sh[256];
  int tid = threadIdx.x;
  int base = blockIdx.x * 1024 + tid * 4;
  int v0 = (base + 0 < n) ? c[base + 0] : 0;
  int v1 = (base + 1 < n) ? c[base + 1] : 0;
  int v2 = (base + 2 < n) ? c[base + 2] : 0;
  int v3 = (base + 3 < n) ? c[base + 3] : 0;
  int s = v0 + v1 + v2 + v3;
  sh[tid] = s;
  __syncthreads();
  for (int off = 1; off < 256; off <<= 1) {
    int t = (tid >= off) ? sh[tid - off] : 0;
    __syncthreads();
    sh[tid] += t;
    __syncthreads();
  }
  int excl = sh[tid] - s;
  if (tid == 255) bsum[blockIdx.x] = sh[tid];
  if (base + 0 < n) rs[base + 0] = excl;
  if (base + 1 < n) rs[base + 1] = excl + v0;
  if (base + 2 < n) rs[base + 2] = excl + v0 + v1;
  if (base + 3 < n) rs[base + 3] = excl + v0 + v1 + v2;
}

__global__ void k_scan2(int* __restrict__ bsum, int nb) {  // nb <= 128
  __shared__ int sh[128];
  int tid = threadIdx.x;
  int v = (tid < nb) ? bsum[tid] : 0;
  sh[tid] = v;
  __syncthreads();
  for (int off = 1; off < 128; off <<= 1) {
    int t = (tid >= off) ? sh[tid - off] : 0;
    __syncthreads();
    sh[tid] += t;
    __syncthreads();
  }
  if (tid < nb) bsum[tid] = sh[tid] - v;  // exclusive
}

__global__ void k_scan3(int* __restrict__ rs, const int* __restrict__ bsum, int n) {
  int i = blockIdx.x * 256 + threadIdx.x;
  if (i < n) rs[i] += bsum[i >> 10];
}

__global__ void k_fill(const int* __restrict__ src, const int* __restrict__ dst,
                       const int* __restrict__ rs, int* __restrict__ cursor,
                       int* __restrict__ col, int E) {
  int e = blockIdx.x * 256 + threadIdx.x;
  if (e < E) {
    int d = dst[e];
    int p = rs[d] + atomicAdd(&cursor[d], 1);
    col[p] = src[e];
  }
}

// --- GEMM1: g1[row] = dinv[row] * (x[row,0:64] @ W1[64,128]) ---
__global__ __launch_bounds__(256) void k_gemm1(const float* __restrict__ x,
                                               const float* __restrict__ W,
                                               const float* __restrict__ dinv,
                                               float* __restrict__ g, int n) {
  __shared__ float4 w4[64 * 32];   // W[k][c] as float4 over c: 32KB
  __shared__ float4 xs4[8 * 16];   // 8 rows x 64 cols: 2KB
  int tid = threadIdx.x;
  const float4* Wv = reinterpret_cast<const float4*>(W);
  for (int i = tid; i < 64 * 32; i += 256) w4[i] = Wv[i];
  int trow = tid >> 5, tcol = tid & 31;
  int ntiles = n >> 3;  // n % 8 == 0 for N=100000
  for (int tile = blockIdx.x; tile < ntiles; tile += gridDim.x) {
    int row0 = tile * 8;
    __syncthreads();
    if (tid < 128) xs4[tid] = reinterpret_cast<const float4*>(x + (size_t)row0 * 64)[tid];
    __syncthreads();
    float4 acc = {0.f, 0.f, 0.f, 0.f};
#pragma unroll
    for (int k4 = 0; k4 < 16; ++k4) {
      float4 xv = xs4[trow * 16 + k4];
      float4 wa = w4[(k4 * 4 + 0) * 32 + tcol];
      float4 wb = w4[(k4 * 4 + 1) * 32 + tcol];
      float4 wc = w4[(k4 * 4 + 2) * 32 + tcol];
      float4 wd = w4[(k4 * 4 + 3) * 32 + tcol];
      acc.x = fmaf(xv.x, wa.x, acc.x); acc.y = fmaf(xv.x, wa.y, acc.y);
      acc.z = fmaf(xv.x, wa.z, acc.z); acc.w = fmaf(xv.x, wa.w, acc.w);
      acc.x = fmaf(xv.y, wb.x, acc.x); acc.y = fmaf(xv.y, wb.y, acc.y);
      acc.z = fmaf(xv.y, wb.z, acc.z); acc.w = fmaf(xv.y, wb.w, acc.w);
      acc.x = fmaf(xv.z, wc.x, acc.x); acc.y = fmaf(xv.z, wc.y, acc.y);
      acc.z = fmaf(xv.z, wc.z, acc.z); acc.w = fmaf(xv.z, wc.w, acc.w);
      acc.x = fmaf(xv.w, wd.x, acc.x); acc.y = fmaf(xv.w, wd.y, acc.y);
      acc.z = fmaf(xv.w, wd.z, acc.z); acc.w = fmaf(xv.w, wd.w, acc.w);
    }
    int row = row0 + trow;
    float di = dinv[row];
    float4 o = {acc.x * di, acc.y * di, acc.z * di, acc.w * di};
    reinterpret_cast<float4*>(g + (size_t)row * 128)[tcol] = o;
  }
}

// --- GEMM2: g2[row] = dinv[row] * (h1[row,0:128] @ W2[128,64]) ---
__global__ __launch_bounds__(256) void k_gemm2(const float* __restrict__ h1,
                                               const float* __restrict__ W,
                                               const float* __restrict__ dinv,
                                               float* __restrict__ g, int n) {
  __shared__ float4 w4[128 * 16];  // W[k][c]: 32KB
  __shared__ float4 xs4[16 * 32];  // 16 rows x 128 cols: 8KB
  int tid = threadIdx.x;
  const float4* Wv = reinterpret_cast<const float4*>(W);
  for (int i = tid; i < 128 * 16; i += 256) w4[i] = Wv[i];
  int trow = tid >> 4, tcol = tid & 15;
  int ntiles = n >> 4;  // n % 16 == 0
  for (int tile = blockIdx.x; tile < ntiles; tile += gridDim.x) {
    int row0 = tile * 16;
    __syncthreads();
    {
      const float4* xp = reinterpret_cast<const float4*>(h1 + (size_t)row0 * 128);
      xs4[tid] = xp[tid];
      xs4[tid + 256] = xp[tid + 256];
    }
    __syncthreads();
    float4 acc = {0.f, 0.f, 0.f, 0.f};
#pragma unroll
    for (int k4 = 0; k4 < 32; ++k4) {
      float4 xv = xs4[trow * 32 + k4];
      float4 wa = w4[(k4 * 4 + 0) * 16 + tcol];
      float4 wb = w4[(k4 * 4 + 1) * 16 + tcol];
      float4 wc = w4[(k4 * 4 + 2) * 16 + tcol];
      float4 wd = w4[(k4 * 4 + 3) * 16 + tcol];
      acc.x = fmaf(xv.x, wa.x, acc.x); acc.y = fmaf(xv.x, wa.y, acc.y);
      acc.z = fmaf(xv.x, wa.z, acc.z); acc.w = fmaf(xv.x, wa.w, acc.w);
      acc.x = fmaf(xv.y, wb.x, acc.x); acc.y = fmaf(xv.y, wb.y, acc.y);
      acc.z = fmaf(xv.y, wb.z, acc.z); acc.w = fmaf(xv.y, wb.w, acc.w);
      acc.x = fmaf(xv.z, wc.x, acc.x); acc.y = fmaf(xv.z, wc.y, acc.y);
      acc.z = fmaf(xv.z, wc.z, acc.z); acc.w = fmaf(xv.z, wc.w, acc.w);
      acc.x = fmaf(xv.w, wd.x, acc.x); acc.y = fmaf(xv.w, wd.y, acc.y);
      acc.z = fmaf(xv.w, wd.z, acc.z); acc.w = fmaf(xv.w, wd.w, acc.w);
    }
    int row = row0 + trow;
    float di = dinv[row];
    float4 o = {acc.x * di, acc.y * di, acc.z * di, acc.w * di};
    reinterpret_cast<float4*>(g + (size_t)row * 64)[tcol] = o;
  }
}

// --- Pull layer 1 (F=128): one wave per node, lane owns float2 of the row ---
__global__ __launch_bounds__(256) void k_pull1(const float* __restrict__ g,
                                               const int* __restrict__ rs,
                                               const int* __restrict__ cnt,
                                               const int* __restrict__ col,
                                               const float* __restrict__ dinv,
                                               const float* __restrict__ b,
                                               float* __restrict__ h, int n) {
  int node = (blockIdx.x * 256 + threadIdx.x) >> 6;
  int lane = threadIdx.x & 63;
  if (node >= n) return;
  const float2* gp = reinterpret_cast<const float2*>(g);
  float2 acc = gp[(size_t)node * 64 + lane];  // self-loop term g[i]
  int start = rs[node], m = cnt[node];
  for (int base0 = 0; base0 < m; base0 += 64) {
    int lim = min(64, m - base0);
    int idx = (lane < lim) ? col[start + base0 + lane] : 0;
    int j = 0;
    for (; j + 4 <= lim; j += 4) {
      int s0 = __shfl(idx, j + 0), s1 = __shfl(idx, j + 1);
      int s2 = __shfl(idx, j + 2), s3 = __shfl(idx, j + 3);
      float2 a0 = gp[(size_t)s0 * 64 + lane];
      float2 a1 = gp[(size_t)s1 * 64 + lane];
      float2 a2 = gp[(size_t)s2 * 64 + lane];
      float2 a3 = gp[(size_t)s3 * 64 + lane];
      acc.x += (a0.x + a1.x) + (a2.x + a3.x);
      acc.y += (a0.y + a1.y) + (a2.y + a3.y);
    }
    for (; j < lim; ++j) {
      int s0 = __shfl(idx, j);
      float2 a0 = gp[(size_t)s0 * 64 + lane];
      acc.x += a0.x;
      acc.y += a0.y;
    }
  }
  float di = dinv[node];
  float2 bb = reinterpret_cast<const float2*>(b)[lane];
  float hx = fmaxf(fmaf(acc.x, di, bb.x), 0.0f);
  float hy = fmaxf(fmaf(acc.y, di, bb.y), 0.0f);
  reinterpret_cast<float2*>(h)[(size_t)node * 64 + lane] = make_float2(hx, hy);
}

// --- Pull layer 2 (F=64) fused with both heads; h2 never materialized ---
__global__ __launch_bounds__(256) void k_pull2(const float* __restrict__ g,
                                               const int* __restrict__ rs,
                                               const int* __restrict__ cnt,
                                               const int* __restrict__ col,
                                               const float* __restrict__ dinv,
                                               const float* __restrict__ b,
                                               const float* __restrict__ Wd,
                                               const float* __restrict__ Wp,
                                               const float* __restrict__ bd,
                                               const float* __restrict__ bp,
                                               float* __restrict__ out, int n) {
  int node = (blockIdx.x * 256 + threadIdx.x) >> 6;
  int lane = threadIdx.x & 63;
  if (node >= n) return;
  float acc = g[(size_t)node * 64 + lane];  // self-loop term
  int start = rs[node], m = cnt[node];
  for (int base0 = 0; base0 < m; base0 += 64) {
    int lim = min(64, m - base0);
    int idx = (lane < lim) ? col[start + base0 + lane] : 0;
    int j = 0;
    for (; j + 4 <= lim; j += 4) {
      int s0 = __shfl(idx, j + 0), s1 = __shfl(idx, j + 1);
      int s2 = __shfl(idx, j + 2), s3 = __shfl(idx, j + 3);
      float a0 = g[(size_t)s0 * 64 + lane];
      float a1 = g[(size_t)s1 * 64 + lane];
      float a2 = g[(size_t)s2 * 64 + lane];
      float a3 = g[(size_t)s3 * 64 + lane];
      acc += (a0 + a1) + (a2 + a3);
    }
    for (; j < lim; ++j) {
      int s0 = __shfl(idx, j);
      acc += g[(size_t)s0 * 64 + lane];
    }
  }
  float v = fmaxf(fmaf(acc, dinv[node], b[lane]), 0.0f);  // h2 row element
  float dsum = v * Wd[lane];
  float psum = v * Wp[lane];
#pragma unroll
  for (int off = 32; off > 0; off >>= 1) {
    dsum += __shfl_xor(dsum, off);
    psum += __shfl_xor(psum, off);
  }
  if (lane == 0) {
    out[node] = dsum + bd[0];
    out[n + node] = psum + bp[0];
  }
}

extern "C" void kernel_launch(void* const* d_in, const int* in_sizes, int n_in,
                              void* d_out, int out_size, void* d_ws, size_t ws_size,
                              hipStream_t stream) {
  const float* x  = (const float*)d_in[0];
  const int*   ei = (const int*)d_in[1];
  const float* W1 = (const float*)d_in[2];
  const float* b1 = (const float*)d_in[3];
  const float* W2 = (const float*)d_in[4];
  const float* b2 = (const float*)d_in[5];
  const float* Wd = (const float*)d_in[6];
  const float* bd = (const float*)d_in[7];
  const float* Wp = (const float*)d_in[8];
  const float* bp = (const float*)d_in[9];
  float* out = (float*)d_out;

  const int N = in_sizes[0] / 64;
  const int E = in_sizes[1] / 2;
  const int* src = ei;
  const int* dst = ei + E;

  char* ws = (char*)d_ws;
  size_t off = 0;
  auto alloc = [&](size_t bytes) -> void* {
    size_t a = (off + 255) & ~(size_t)255;
    off = a + bytes;
    return (void*)(ws + a);
  };

  int*   c      = (int*)alloc((size_t)N * 8);  // c then cursor, one memset
  int*   cursor = c + N;
  int*   rs     = (int*)alloc((size_t)N * 4);
  int*   bsum   = (int*)alloc(1024);
  float* dinv   = (float*)alloc((size_t)N * 4);
  int*   col    = (int*)alloc((size_t)E * 4);
  float* g1     = (float*)alloc((size_t)N * 128 * 4);
  float* h1     = (float*)alloc((size_t)N * 128 * 4);
  float* g2     = (float*)alloc((size_t)N * 64 * 4);
  (void)ws_size; (void)n_in; (void)out_size;

  hipMemsetAsync(c, 0, (size_t)N * 8, stream);

  k_deg<<<(E + 255) / 256, 256, 0, stream>>>(dst, c, E);
  k_dinv<<<(N + 255) / 256, 256, 0, stream>>>(c, dinv, N);

  int nb = (N + 1023) / 1024;  // 98 for N=100000 (<=128 required by k_scan2)
  k_scan1<<<nb, 256, 0, stream>>>(c, rs, bsum, N);
  k_scan2<<<1, 128, 0, stream>>>(bsum, nb);
  k_scan3<<<(N + 255) / 256, 256, 0, stream>>>(rs, bsum, N);
  k_fill<<<(E + 255) / 256, 256, 0, stream>>>(src, dst, rs, cursor, col, E);

  k_gemm1<<<2048, 256, 0, stream>>>(x, W1, dinv, g1, N);
  k_pull1<<<(N + 3) / 4, 256, 0, stream>>>(g1, rs, c, col, dinv, b1, h1, N);
  k_gemm2<<<2048, 256, 0, stream>>>(h1, W2, dinv, g2, N);
  k_pull2<<<(N + 3) / 4, 256, 0, stream>>>(g2, rs, c, col, dinv, b2, Wd, Wp, bd, bp, out, N);
}

// Round 2
// 427.790 us; speedup vs baseline: 1.2291x; 1.2291x over previous
//
#include <hip/hip_runtime.h>
#include <cstdint>
#include <cstddef>

// ---------------------------------------------------------------------------
// GCN 2-layer + 2 heads. N=100000, E=1.6M.
//   layer1: agg = Â x (aggregate FIRST, 64-dim)  ->  h1 = relu(agg@W1 + b1)
//   layer2: g2 = dinv ⊙ (h1@W2)                  ->  out heads fused in pull2
// CSR built via two-level counting sort (64-node buckets); bucket region of
// col starts at rs[b*64] so bucket cursors init straight from rs.
// ---------------------------------------------------------------------------

#define MAXB 2048  // max buckets (N <= 131072)

__global__ void k_deg(const int* __restrict__ dst, int* __restrict__ c, int E) {
  int e = blockIdx.x * 256 + threadIdx.x;
  if (e < E) atomicAdd(&c[dst[e]], 1);
}

__global__ void k_dinv(const int* __restrict__ c, float* __restrict__ dinv, int n) {
  int i = blockIdx.x * 256 + threadIdx.x;
  if (i < n) dinv[i] = rsqrtf((float)(c[i] + 1));
}

// --- exclusive scan of c -> rs ---
__global__ void k_scan1(const int* __restrict__ c, int* __restrict__ rs,
                        int* __restrict__ bsum, int n) {
  __shared__ int sh[256];
  int tid = threadIdx.x;
  int base = blockIdx.x * 1024 + tid * 4;
  int v0 = (base + 0 < n) ? c[base + 0] : 0;
  int v1 = (base + 1 < n) ? c[base + 1] : 0;
  int v2 = (base + 2 < n) ? c[base + 2] : 0;
  int v3 = (base + 3 < n) ? c[base + 3] : 0;
  int s = v0 + v1 + v2 + v3;
  sh[tid] = s;
  __syncthreads();
  for (int off = 1; off < 256; off <<= 1) {
    int t = (tid >= off) ? sh[tid - off] : 0;
    __syncthreads();
    sh[tid] += t;
    __syncthreads();
  }
  int excl = sh[tid] - s;
  if (tid == 255) bsum[blockIdx.x] = sh[tid];
  if (base + 0 < n) rs[base + 0] = excl;
  if (base + 1 < n) rs[base + 1] = excl + v0;
  if (base + 2 < n) rs[base + 2] = excl + v0 + v1;
  if (base + 3 < n) rs[base + 3] = excl + v0 + v1 + v2;
}

__global__ void k_scan2(int* __restrict__ bsum, int nb) {  // nb <= 128
  __shared__ int sh[128];
  int tid = threadIdx.x;
  int v = (tid < nb) ? bsum[tid] : 0;
  sh[tid] = v;
  __syncthreads();
  for (int off = 1; off < 128; off <<= 1) {
    int t = (tid >= off) ? sh[tid - off] : 0;
    __syncthreads();
    sh[tid] += t;
    __syncthreads();
  }
  if (tid < nb) bsum[tid] = sh[tid] - v;
}

__global__ void k_scan3(int* __restrict__ rs, const int* __restrict__ bsum, int n) {
  int i = blockIdx.x * 256 + threadIdx.x;
  if (i < n) rs[i] += bsum[i >> 10];
}

// --- bucket cursors init: region of bucket b in col starts at rs[b*64] ---
__global__ void k_initcur(const int* __restrict__ rs, int* __restrict__ gcur, int nbkt) {
  int b = blockIdx.x * 256 + threadIdx.x;
  if (b < nbkt) gcur[b] = rs[b << 6];
}

// --- coarse counting sort into 64-node buckets: S[p]=src, D8[p]=dst&63 ---
__global__ __launch_bounds__(256) void k_bucket(const int* __restrict__ src,
                                                const int* __restrict__ dst,
                                                int* __restrict__ gcur,
                                                int* __restrict__ S,
                                                unsigned char* __restrict__ D8,
                                                int E, int nbkt, int seg) {
  __shared__ int hist[MAXB];
  __shared__ int bcur[MAXB];
  int tid = threadIdx.x;
  int start = blockIdx.x * seg;
  int end = min(E, start + seg);
  for (int i = tid; i < nbkt; i += 256) hist[i] = 0;
  __syncthreads();
  for (int i = start + tid; i < end; i += 256)
    atomicAdd(&hist[dst[i] >> 6], 1);
  __syncthreads();
  for (int b = tid; b < nbkt; b += 256) {
    int h = hist[b];
    bcur[b] = h ? atomicAdd(&gcur[b], h) : 0;
  }
  __syncthreads();
  for (int i = start + tid; i < end; i += 256) {
    int d = dst[i];
    int p = atomicAdd(&bcur[d >> 6], 1);
    S[p] = src[i];
    D8[p] = (unsigned char)(d & 63);
  }
}

// --- fine fill within each bucket: block-per-bucket, LDS node cursors ---
__global__ __launch_bounds__(256) void k_fill2(const int* __restrict__ S,
                                               const unsigned char* __restrict__ D8,
                                               const int* __restrict__ rs,
                                               int* __restrict__ col, int N, int E) {
  __shared__ int lcur[64];
  int tid = threadIdx.x;
  int node0 = blockIdx.x << 6;
  if (tid < 64) lcur[tid] = 0;
  int begin = rs[node0];
  int hi = node0 + 64;
  int end = (hi >= N) ? E : rs[hi];
  __syncthreads();
  for (int i = begin + tid; i < end; i += 256) {
    int lo = D8[i];
    int p = rs[node0 + lo] + atomicAdd(&lcur[lo], 1);
    col[p] = S[i];
  }
}

// --- pull layer 1 in INPUT space (F=64): agg = dinv*(sum dinv_s*x_s + dinv_i*x_i) ---
__global__ __launch_bounds__(256) void k_pull1(const float* __restrict__ x,
                                               const int* __restrict__ rs,
                                               const int* __restrict__ cnt,
                                               const int* __restrict__ col,
                                               const float* __restrict__ dinv,
                                               float* __restrict__ agg, int n) {
  int node = (blockIdx.x * 256 + threadIdx.x) >> 6;
  int lane = threadIdx.x & 63;
  if (node >= n) return;
  float di = dinv[node];
  float acc = di * x[(size_t)node * 64 + lane];
  int start = rs[node], m = cnt[node];
  for (int base0 = 0; base0 < m; base0 += 64) {
    int lim = min(64, m - base0);
    int idx = 0;
    float dv = 0.f;
    if (lane < lim) {
      idx = col[start + base0 + lane];
      dv = dinv[idx];
    }
    int j = 0;
    for (; j + 8 <= lim; j += 8) {
      int s0 = __shfl(idx, j + 0), s1 = __shfl(idx, j + 1);
      int s2 = __shfl(idx, j + 2), s3 = __shfl(idx, j + 3);
      int s4 = __shfl(idx, j + 4), s5 = __shfl(idx, j + 5);
      int s6 = __shfl(idx, j + 6), s7 = __shfl(idx, j + 7);
      float w0 = __shfl(dv, j + 0), w1 = __shfl(dv, j + 1);
      float w2 = __shfl(dv, j + 2), w3 = __shfl(dv, j + 3);
      float w4 = __shfl(dv, j + 4), w5 = __shfl(dv, j + 5);
      float w6 = __shfl(dv, j + 6), w7 = __shfl(dv, j + 7);
      float a0 = x[(size_t)s0 * 64 + lane];
      float a1 = x[(size_t)s1 * 64 + lane];
      float a2 = x[(size_t)s2 * 64 + lane];
      float a3 = x[(size_t)s3 * 64 + lane];
      float a4 = x[(size_t)s4 * 64 + lane];
      float a5 = x[(size_t)s5 * 64 + lane];
      float a6 = x[(size_t)s6 * 64 + lane];
      float a7 = x[(size_t)s7 * 64 + lane];
      acc = fmaf(w0, a0, acc); acc = fmaf(w1, a1, acc);
      acc = fmaf(w2, a2, acc); acc = fmaf(w3, a3, acc);
      acc = fmaf(w4, a4, acc); acc = fmaf(w5, a5, acc);
      acc = fmaf(w6, a6, acc); acc = fmaf(w7, a7, acc);
    }
    for (; j < lim; ++j) {
      int s0 = __shfl(idx, j);
      float w0 = __shfl(dv, j);
      acc = fmaf(w0, x[(size_t)s0 * 64 + lane], acc);
    }
  }
  agg[(size_t)node * 64 + lane] = di * acc;
}

// --- GEMM1: h1 = relu(agg[N,64] @ W1[64,128] + b1) ---
__global__ __launch_bounds__(256) void k_gemm1(const float* __restrict__ A,
                                               const float* __restrict__ W,
                                               const float* __restrict__ b,
                                               float* __restrict__ h, int n) {
  __shared__ float4 w4[64 * 32];
  __shared__ float4 xs4[8 * 16];
  __shared__ float4 bb[32];
  int tid = threadIdx.x;
  const float4* Wv = reinterpret_cast<const float4*>(W);
  for (int i = tid; i < 64 * 32; i += 256) w4[i] = Wv[i];
  if (tid < 32) bb[tid] = reinterpret_cast<const float4*>(b)[tid];
  int trow = tid >> 5, tcol = tid & 31;
  int ntiles = n >> 3;
  for (int tile = blockIdx.x; tile < ntiles; tile += gridDim.x) {
    int row0 = tile * 8;
    __syncthreads();
    if (tid < 128) xs4[tid] = reinterpret_cast<const float4*>(A + (size_t)row0 * 64)[tid];
    __syncthreads();
    float4 acc = {0.f, 0.f, 0.f, 0.f};
#pragma unroll
    for (int k4 = 0; k4 < 16; ++k4) {
      float4 xv = xs4[trow * 16 + k4];
      float4 wa = w4[(k4 * 4 + 0) * 32 + tcol];
      float4 wb = w4[(k4 * 4 + 1) * 32 + tcol];
      float4 wc = w4[(k4 * 4 + 2) * 32 + tcol];
      float4 wd = w4[(k4 * 4 + 3) * 32 + tcol];
      acc.x = fmaf(xv.x, wa.x, acc.x); acc.y = fmaf(xv.x, wa.y, acc.y);
      acc.z = fmaf(xv.x, wa.z, acc.z); acc.w = fmaf(xv.x, wa.w, acc.w);
      acc.x = fmaf(xv.y, wb.x, acc.x); acc.y = fmaf(xv.y, wb.y, acc.y);
      acc.z = fmaf(xv.y, wb.z, acc.z); acc.w = fmaf(xv.y, wb.w, acc.w);
      acc.x = fmaf(xv.z, wc.x, acc.x); acc.y = fmaf(xv.z, wc.y, acc.y);
      acc.z = fmaf(xv.z, wc.z, acc.z); acc.w = fmaf(xv.z, wc.w, acc.w);
      acc.x = fmaf(xv.w, wd.x, acc.x); acc.y = fmaf(xv.w, wd.y, acc.y);
      acc.z = fmaf(xv.w, wd.z, acc.z); acc.w = fmaf(xv.w, wd.w, acc.w);
    }
    int row = row0 + trow;
    float4 bv = bb[tcol];
    float4 o = {fmaxf(acc.x + bv.x, 0.f), fmaxf(acc.y + bv.y, 0.f),
                fmaxf(acc.z + bv.z, 0.f), fmaxf(acc.w + bv.w, 0.f)};
    reinterpret_cast<float4*>(h + (size_t)row * 128)[tcol] = o;
  }
}

// --- GEMM2: g2 = dinv ⊙ (h1[N,128] @ W2[128,64]) ---
__global__ __launch_bounds__(256) void k_gemm2(const float* __restrict__ h1,
                                               const float* __restrict__ W,
                                               const float* __restrict__ dinv,
                                               float* __restrict__ g, int n) {
  __shared__ float4 w4[128 * 16];
  __shared__ float4 xs4[16 * 32];
  int tid = threadIdx.x;
  const float4* Wv = reinterpret_cast<const float4*>(W);
  for (int i = tid; i < 128 * 16; i += 256) w4[i] = Wv[i];
  int trow = tid >> 4, tcol = tid & 15;
  int ntiles = n >> 4;
  for (int tile = blockIdx.x; tile < ntiles; tile += gridDim.x) {
    int row0 = tile * 16;
    __syncthreads();
    {
      const float4* xp = reinterpret_cast<const float4*>(h1 + (size_t)row0 * 128);
      xs4[tid] = xp[tid];
      xs4[tid + 256] = xp[tid + 256];
    }
    __syncthreads();
    float4 acc = {0.f, 0.f, 0.f, 0.f};
#pragma unroll
    for (int k4 = 0; k4 < 32; ++k4) {
      float4 xv = xs4[trow * 32 + k4];
      float4 wa = w4[(k4 * 4 + 0) * 16 + tcol];
      float4 wb = w4[(k4 * 4 + 1) * 16 + tcol];
      float4 wc = w4[(k4 * 4 + 2) * 16 + tcol];
      float4 wd = w4[(k4 * 4 + 3) * 16 + tcol];
      acc.x = fmaf(xv.x, wa.x, acc.x); acc.y = fmaf(xv.x, wa.y, acc.y);
      acc.z = fmaf(xv.x, wa.z, acc.z); acc.w = fmaf(xv.x, wa.w, acc.w);
      acc.x = fmaf(xv.y, wb.x, acc.x); acc.y = fmaf(xv.y, wb.y, acc.y);
      acc.z = fmaf(xv.y, wb.z, acc.z); acc.w = fmaf(xv.y, wb.w, acc.w);
      acc.x = fmaf(xv.z, wc.x, acc.x); acc.y = fmaf(xv.z, wc.y, acc.y);
      acc.z = fmaf(xv.z, wc.z, acc.z); acc.w = fmaf(xv.z, wc.w, acc.w);
      acc.x = fmaf(xv.w, wd.x, acc.x); acc.y = fmaf(xv.w, wd.y, acc.y);
      acc.z = fmaf(xv.w, wd.z, acc.z); acc.w = fmaf(xv.w, wd.w, acc.w);
    }
    int row = row0 + trow;
    float di = dinv[row];
    float4 o = {acc.x * di, acc.y * di, acc.z * di, acc.w * di};
    reinterpret_cast<float4*>(g + (size_t)row * 64)[tcol] = o;
  }
}

// --- pull layer 2 (F=64) + both heads fused; h2 never materialized ---
__global__ __launch_bounds__(256) void k_pull2(const float* __restrict__ g,
                                               const int* __restrict__ rs,
                                               const int* __restrict__ cnt,
                                               const int* __restrict__ col,
                                               const float* __restrict__ dinv,
                                               const float* __restrict__ b,
                                               const float* __restrict__ Wd,
                                               const float* __restrict__ Wp,
                                               const float* __restrict__ bd,
                                               const float* __restrict__ bp,
                                               float* __restrict__ out, int n) {
  int node = (blockIdx.x * 256 + threadIdx.x) >> 6;
  int lane = threadIdx.x & 63;
  if (node >= n) return;
  float acc = g[(size_t)node * 64 + lane];
  int start = rs[node], m = cnt[node];
  for (int base0 = 0; base0 < m; base0 += 64) {
    int lim = min(64, m - base0);
    int idx = (lane < lim) ? col[start + base0 + lane] : 0;
    int j = 0;
    for (; j + 8 <= lim; j += 8) {
      int s0 = __shfl(idx, j + 0), s1 = __shfl(idx, j + 1);
      int s2 = __shfl(idx, j + 2), s3 = __shfl(idx, j + 3);
      int s4 = __shfl(idx, j + 4), s5 = __shfl(idx, j + 5);
      int s6 = __shfl(idx, j + 6), s7 = __shfl(idx, j + 7);
      float a0 = g[(size_t)s0 * 64 + lane];
      float a1 = g[(size_t)s1 * 64 + lane];
      float a2 = g[(size_t)s2 * 64 + lane];
      float a3 = g[(size_t)s3 * 64 + lane];
      float a4 = g[(size_t)s4 * 64 + lane];
      float a5 = g[(size_t)s5 * 64 + lane];
      float a6 = g[(size_t)s6 * 64 + lane];
      float a7 = g[(size_t)s7 * 64 + lane];
      acc += ((a0 + a1) + (a2 + a3)) + ((a4 + a5) + (a6 + a7));
    }
    for (; j < lim; ++j) {
      int s0 = __shfl(idx, j);
      acc += g[(size_t)s0 * 64 + lane];
    }
  }
  float v = fmaxf(fmaf(acc, dinv[node], b[lane]), 0.0f);
  float dsum = v * Wd[lane];
  float psum = v * Wp[lane];
#pragma unroll
  for (int off = 32; off > 0; off >>= 1) {
    dsum += __shfl_xor(dsum, off);
    psum += __shfl_xor(psum, off);
  }
  if (lane == 0) {
    out[node] = dsum + bd[0];
    out[n + node] = psum + bp[0];
  }
}

extern "C" void kernel_launch(void* const* d_in, const int* in_sizes, int n_in,
                              void* d_out, int out_size, void* d_ws, size_t ws_size,
                              hipStream_t stream) {
  const float* x  = (const float*)d_in[0];
  const int*   ei = (const int*)d_in[1];
  const float* W1 = (const float*)d_in[2];
  const float* b1 = (const float*)d_in[3];
  const float* W2 = (const float*)d_in[4];
  const float* b2 = (const float*)d_in[5];
  const float* Wd = (const float*)d_in[6];
  const float* bd = (const float*)d_in[7];
  const float* Wp = (const float*)d_in[8];
  const float* bp = (const float*)d_in[9];
  float* out = (float*)d_out;

  const int N = in_sizes[0] / 64;
  const int E = in_sizes[1] / 2;
  const int* src = ei;
  const int* dst = ei + E;
  const int nbkt = (N + 63) >> 6;  // 1563 for N=100000 (<= MAXB)

  char* ws = (char*)d_ws;
  size_t off = 0;
  auto alloc = [&](size_t bytes) -> void* {
    size_t a = (off + 255) & ~(size_t)255;
    off = a + bytes;
    return (void*)(ws + a);
  };

  int*   c    = (int*)alloc((size_t)N * 4);
  int*   rs   = (int*)alloc((size_t)N * 4);
  int*   bsum = (int*)alloc(1024);
  float* dinv = (float*)alloc((size_t)N * 4);
  int*   gcur = (int*)alloc((size_t)MAXB * 4);
  int*   col  = (int*)alloc((size_t)E * 4);
  int*   S    = (int*)alloc((size_t)E * 4);
  unsigned char* D8 = (unsigned char*)alloc((size_t)E);
  float* agg  = (float*)alloc((size_t)N * 64 * 4);  // reused as g2 after gemm1
  float* h1   = (float*)alloc((size_t)N * 128 * 4);
  float* g2   = agg;  // agg dead once gemm1 has consumed it
  (void)ws_size; (void)n_in; (void)out_size;

  hipMemsetAsync(c, 0, (size_t)N * 4, stream);

  k_deg<<<(E + 255) / 256, 256, 0, stream>>>(dst, c, E);
  k_dinv<<<(N + 255) / 256, 256, 0, stream>>>(c, dinv, N);

  int nb = (N + 1023) / 1024;  // 98 <= 128
  k_scan1<<<nb, 256, 0, stream>>>(c, rs, bsum, N);
  k_scan2<<<1, 128, 0, stream>>>(bsum, nb);
  k_scan3<<<(N + 255) / 256, 256, 0, stream>>>(rs, bsum, N);

  k_initcur<<<(nbkt + 255) / 256, 256, 0, stream>>>(rs, gcur, nbkt);
  int seg = (E + 127) / 128;
  k_bucket<<<128, 256, 0, stream>>>(src, dst, gcur, S, D8, E, nbkt, seg);
  k_fill2<<<nbkt, 256, 0, stream>>>(S, D8, rs, col, N, E);

  k_pull1<<<(N + 3) / 4, 256, 0, stream>>>(x, rs, c, col, dinv, agg, N);
  k_gemm1<<<2048, 256, 0, stream>>>(agg, W1, b1, h1, N);
  k_gemm2<<<2048, 256, 0, stream>>>(h1, W2, dinv, g2, N);
  k_pull2<<<(N + 3) / 4, 256, 0, stream>>>(g2, rs, c, col, dinv, b2, Wd, Wp, bd, bp, out, N);
}

// Round 3
// 406.628 us; speedup vs baseline: 1.2931x; 1.0520x over previous
//
#include <hip/hip_runtime.h>
#include <cstdint>
#include <cstddef>

// ---------------------------------------------------------------------------
// GCN 2-layer + 2 heads. N=100000 (<2^17), E=1.6M.
//   layer1: agg = Â x (aggregate first, 64-dim) -> h1 = relu(agg@W1 + b1)
//   layer2: g2 = dinv ⊙ (h1@W2)                 -> heads fused in pull2
// CSR build: two-level radix. Coarse: scatter packed (src | dstlo<<17) into
// 256-node buckets (dense-ish 32B runs). Fine: block-per-bucket, LDS cursors
// init from rs, col writes stay inside a 16KB L2-resident region.
// Pulls: wave-per-node, 16 lanes x float4 per edge, 4 edges per 1KB wave-load.
// ---------------------------------------------------------------------------

#define MAXC 512  // max coarse buckets (N <= 131072)

__global__ void k_deg(const int* __restrict__ dst, int* __restrict__ c, int E) {
  int e = blockIdx.x * 256 + threadIdx.x;
  if (e < E) atomicAdd(&c[dst[e]], 1);
}

__global__ void k_dinv(const int* __restrict__ c, float* __restrict__ dinv, int n) {
  int i = blockIdx.x * 256 + threadIdx.x;
  if (i < n) dinv[i] = rsqrtf((float)(c[i] + 1));
}

// --- exclusive scan of c -> rs ---
__global__ void k_scan1(const int* __restrict__ c, int* __restrict__ rs,
                        int* __restrict__ bsum, int n) {
  __shared__ int sh[256];
  int tid = threadIdx.x;
  int base = blockIdx.x * 1024 + tid * 4;
  int v0 = (base + 0 < n) ? c[base + 0] : 0;
  int v1 = (base + 1 < n) ? c[base + 1] : 0;
  int v2 = (base + 2 < n) ? c[base + 2] : 0;
  int v3 = (base + 3 < n) ? c[base + 3] : 0;
  int s = v0 + v1 + v2 + v3;
  sh[tid] = s;
  __syncthreads();
  for (int off = 1; off < 256; off <<= 1) {
    int t = (tid >= off) ? sh[tid - off] : 0;
    __syncthreads();
    sh[tid] += t;
    __syncthreads();
  }
  int excl = sh[tid] - s;
  if (tid == 255) bsum[blockIdx.x] = sh[tid];
  if (base + 0 < n) rs[base + 0] = excl;
  if (base + 1 < n) rs[base + 1] = excl + v0;
  if (base + 2 < n) rs[base + 2] = excl + v0 + v1;
  if (base + 3 < n) rs[base + 3] = excl + v0 + v1 + v2;
}

__global__ void k_scan2(int* __restrict__ bsum, int nb) {  // nb <= 128
  __shared__ int sh[128];
  int tid = threadIdx.x;
  int v = (tid < nb) ? bsum[tid] : 0;
  sh[tid] = v;
  __syncthreads();
  for (int off = 1; off < 128; off <<= 1) {
    int t = (tid >= off) ? sh[tid - off] : 0;
    __syncthreads();
    sh[tid] += t;
    __syncthreads();
  }
  if (tid < nb) bsum[tid] = sh[tid] - v;
}

__global__ void k_scan3(int* __restrict__ rs, const int* __restrict__ bsum, int n) {
  int i = blockIdx.x * 256 + threadIdx.x;
  if (i < n) rs[i] += bsum[i >> 10];
}

// --- coarse bucket cursors: region of bucket b starts at rs[b*256] ---
__global__ void k_binit(const int* __restrict__ rs, int* __restrict__ gcur, int nc) {
  int b = blockIdx.x * 256 + threadIdx.x;
  if (b < nc) gcur[b] = rs[b << 8];
}

// --- coarse radix scatter: P[p] = src | (dst&255)<<17, grouped by dst>>8 ---
__global__ __launch_bounds__(256) void k_pass1(const int* __restrict__ src,
                                               const int* __restrict__ dst,
                                               int* __restrict__ gcur,
                                               int* __restrict__ P,
                                               int E, int nc, int seg) {
  __shared__ int hist[MAXC];
  __shared__ int bcur[MAXC];
  int tid = threadIdx.x;
  int start = blockIdx.x * seg;
  int end = min(E, start + seg);
  for (int i = tid; i < nc; i += 256) hist[i] = 0;
  __syncthreads();
  for (int i = start + tid; i < end; i += 256)
    atomicAdd(&hist[dst[i] >> 8], 1);
  __syncthreads();
  for (int b = tid; b < nc; b += 256) {
    int h = hist[b];
    bcur[b] = h ? atomicAdd(&gcur[b], h) : 0;
  }
  __syncthreads();
  for (int i = start + tid; i < end; i += 256) {
    int d = dst[i];
    int p = atomicAdd(&bcur[d >> 8], 1);
    P[p] = src[i] | ((d & 255) << 17);
  }
}

// --- fine fill: block per coarse bucket; LDS cursors start at rs[node] ---
__global__ __launch_bounds__(256) void k_pass2(const int* __restrict__ P,
                                               const int* __restrict__ rs,
                                               int* __restrict__ col, int N, int E) {
  __shared__ int lcur[256];
  int tid = threadIdx.x;
  int node0 = blockIdx.x << 8;
  int nn = min(256, N - node0);
  if (tid < nn) lcur[tid] = rs[node0 + tid];
  int begin = rs[node0];
  int end = (node0 + 256 >= N) ? E : rs[node0 + 256];
  __syncthreads();
  for (int i = begin + tid; i < end; i += 256) {
    int p = P[i];
    int lo = p >> 17;          // upper bits are zero (25-bit pack)
    int pos = atomicAdd(&lcur[lo], 1);
    col[pos] = p & 0x1FFFF;
  }
}

// --- pull layer 1 in input space: agg = dinv*(sum dinv_s*x_s + dinv_i*x_i) ---
__global__ __launch_bounds__(256) void k_pull1(const float* __restrict__ x,
                                               const int* __restrict__ rs,
                                               const int* __restrict__ cnt,
                                               const int* __restrict__ col,
                                               const float* __restrict__ dinv,
                                               float* __restrict__ agg, int n) {
  int node = (blockIdx.x * 256 + threadIdx.x) >> 6;
  int lane = threadIdx.x & 63;
  if (node >= n) return;
  int f4 = (lane & 15) * 4;
  int grp = lane >> 4;
  float di = dinv[node];
  int start = rs[node], m = cnt[node];
  float4 acc = {0.f, 0.f, 0.f, 0.f};
  for (int base0 = 0; base0 < m; base0 += 64) {
    int lim = min(64, m - base0);
    int idx = 0;
    float dv = 0.f;
    if (lane < lim) {
      idx = col[start + base0 + lane];
      dv = dinv[idx];
    }
    int nt = lim >> 2;
    int t = 0;
    for (; t + 2 <= nt; t += 2) {
      int e0 = t * 4 + grp, e1 = e0 + 4;
      int s0 = __shfl(idx, e0), s1 = __shfl(idx, e1);
      float w0 = __shfl(dv, e0), w1 = __shfl(dv, e1);
      float4 v0 = *reinterpret_cast<const float4*>(x + (size_t)s0 * 64 + f4);
      float4 v1 = *reinterpret_cast<const float4*>(x + (size_t)s1 * 64 + f4);
      acc.x = fmaf(w0, v0.x, acc.x); acc.y = fmaf(w0, v0.y, acc.y);
      acc.z = fmaf(w0, v0.z, acc.z); acc.w = fmaf(w0, v0.w, acc.w);
      acc.x = fmaf(w1, v1.x, acc.x); acc.y = fmaf(w1, v1.y, acc.y);
      acc.z = fmaf(w1, v1.z, acc.z); acc.w = fmaf(w1, v1.w, acc.w);
    }
    if (t < nt) {
      int e0 = t * 4 + grp;
      int s0 = __shfl(idx, e0);
      float w0 = __shfl(dv, e0);
      float4 v0 = *reinterpret_cast<const float4*>(x + (size_t)s0 * 64 + f4);
      acc.x = fmaf(w0, v0.x, acc.x); acc.y = fmaf(w0, v0.y, acc.y);
      acc.z = fmaf(w0, v0.z, acc.z); acc.w = fmaf(w0, v0.w, acc.w);
    }
    for (int j = nt * 4; j < lim; ++j) {
      int s0 = __shfl(idx, j);
      float w0 = __shfl(dv, j);
      if (grp == (j & 3)) {
        float4 v0 = *reinterpret_cast<const float4*>(x + (size_t)s0 * 64 + f4);
        acc.x = fmaf(w0, v0.x, acc.x); acc.y = fmaf(w0, v0.y, acc.y);
        acc.z = fmaf(w0, v0.z, acc.z); acc.w = fmaf(w0, v0.w, acc.w);
      }
    }
  }
  // combine the 4 lane-groups
  acc.x += __shfl_xor(acc.x, 16); acc.y += __shfl_xor(acc.y, 16);
  acc.z += __shfl_xor(acc.z, 16); acc.w += __shfl_xor(acc.w, 16);
  acc.x += __shfl_xor(acc.x, 32); acc.y += __shfl_xor(acc.y, 32);
  acc.z += __shfl_xor(acc.z, 32); acc.w += __shfl_xor(acc.w, 32);
  // self-loop + outer dinv scale
  float4 xs = *reinterpret_cast<const float4*>(x + (size_t)node * 64 + f4);
  acc.x = fmaf(di, xs.x, acc.x); acc.y = fmaf(di, xs.y, acc.y);
  acc.z = fmaf(di, xs.z, acc.z); acc.w = fmaf(di, xs.w, acc.w);
  if (lane < 16) {
    float4 o = {acc.x * di, acc.y * di, acc.z * di, acc.w * di};
    *reinterpret_cast<float4*>(agg + (size_t)node * 64 + f4) = o;
  }
}

// --- GEMM1: h1 = relu(agg[N,64] @ W1[64,128] + b1) ---
__global__ __launch_bounds__(256) void k_gemm1(const float* __restrict__ A,
                                               const float* __restrict__ W,
                                               const float* __restrict__ b,
                                               float* __restrict__ h, int n) {
  __shared__ float4 w4[64 * 32];
  __shared__ float4 xs4[8 * 16];
  __shared__ float4 bb[32];
  int tid = threadIdx.x;
  const float4* Wv = reinterpret_cast<const float4*>(W);
  for (int i = tid; i < 64 * 32; i += 256) w4[i] = Wv[i];
  if (tid < 32) bb[tid] = reinterpret_cast<const float4*>(b)[tid];
  int trow = tid >> 5, tcol = tid & 31;
  int ntiles = n >> 3;
  for (int tile = blockIdx.x; tile < ntiles; tile += gridDim.x) {
    int row0 = tile * 8;
    __syncthreads();
    if (tid < 128) xs4[tid] = reinterpret_cast<const float4*>(A + (size_t)row0 * 64)[tid];
    __syncthreads();
    float4 acc = {0.f, 0.f, 0.f, 0.f};
#pragma unroll
    for (int k4 = 0; k4 < 16; ++k4) {
      float4 xv = xs4[trow * 16 + k4];
      float4 wa = w4[(k4 * 4 + 0) * 32 + tcol];
      float4 wb = w4[(k4 * 4 + 1) * 32 + tcol];
      float4 wc = w4[(k4 * 4 + 2) * 32 + tcol];
      float4 wd = w4[(k4 * 4 + 3) * 32 + tcol];
      acc.x = fmaf(xv.x, wa.x, acc.x); acc.y = fmaf(xv.x, wa.y, acc.y);
      acc.z = fmaf(xv.x, wa.z, acc.z); acc.w = fmaf(xv.x, wa.w, acc.w);
      acc.x = fmaf(xv.y, wb.x, acc.x); acc.y = fmaf(xv.y, wb.y, acc.y);
      acc.z = fmaf(xv.y, wb.z, acc.z); acc.w = fmaf(xv.y, wb.w, acc.w);
      acc.x = fmaf(xv.z, wc.x, acc.x); acc.y = fmaf(xv.z, wc.y, acc.y);
      acc.z = fmaf(xv.z, wc.z, acc.z); acc.w = fmaf(xv.z, wc.w, acc.w);
      acc.x = fmaf(xv.w, wd.x, acc.x); acc.y = fmaf(xv.w, wd.y, acc.y);
      acc.z = fmaf(xv.w, wd.z, acc.z); acc.w = fmaf(xv.w, wd.w, acc.w);
    }
    int row = row0 + trow;
    float4 bv = bb[tcol];
    float4 o = {fmaxf(acc.x + bv.x, 0.f), fmaxf(acc.y + bv.y, 0.f),
                fmaxf(acc.z + bv.z, 0.f), fmaxf(acc.w + bv.w, 0.f)};
    reinterpret_cast<float4*>(h + (size_t)row * 128)[tcol] = o;
  }
}

// --- GEMM2: g2 = dinv ⊙ (h1[N,128] @ W2[128,64]) ---
__global__ __launch_bounds__(256) void k_gemm2(const float* __restrict__ h1,
                                               const float* __restrict__ W,
                                               const float* __restrict__ dinv,
                                               float* __restrict__ g, int n) {
  __shared__ float4 w4[128 * 16];
  __shared__ float4 xs4[16 * 32];
  int tid = threadIdx.x;
  const float4* Wv = reinterpret_cast<const float4*>(W);
  for (int i = tid; i < 128 * 16; i += 256) w4[i] = Wv[i];
  int trow = tid >> 4, tcol = tid & 15;
  int ntiles = n >> 4;
  for (int tile = blockIdx.x; tile < ntiles; tile += gridDim.x) {
    int row0 = tile * 16;
    __syncthreads();
    {
      const float4* xp = reinterpret_cast<const float4*>(h1 + (size_t)row0 * 128);
      xs4[tid] = xp[tid];
      xs4[tid + 256] = xp[tid + 256];
    }
    __syncthreads();
    float4 acc = {0.f, 0.f, 0.f, 0.f};
#pragma unroll
    for (int k4 = 0; k4 < 32; ++k4) {
      float4 xv = xs4[trow * 32 + k4];
      float4 wa = w4[(k4 * 4 + 0) * 16 + tcol];
      float4 wb = w4[(k4 * 4 + 1) * 16 + tcol];
      float4 wc = w4[(k4 * 4 + 2) * 16 + tcol];
      float4 wd = w4[(k4 * 4 + 3) * 16 + tcol];
      acc.x = fmaf(xv.x, wa.x, acc.x); acc.y = fmaf(xv.x, wa.y, acc.y);
      acc.z = fmaf(xv.x, wa.z, acc.z); acc.w = fmaf(xv.x, wa.w, acc.w);
      acc.x = fmaf(xv.y, wb.x, acc.x); acc.y = fmaf(xv.y, wb.y, acc.y);
      acc.z = fmaf(xv.y, wb.z, acc.z); acc.w = fmaf(xv.y, wb.w, acc.w);
      acc.x = fmaf(xv.z, wc.x, acc.x); acc.y = fmaf(xv.z, wc.y, acc.y);
      acc.z = fmaf(xv.z, wc.z, acc.z); acc.w = fmaf(xv.z, wc.w, acc.w);
      acc.x = fmaf(xv.w, wd.x, acc.x); acc.y = fmaf(xv.w, wd.y, acc.y);
      acc.z = fmaf(xv.w, wd.z, acc.z); acc.w = fmaf(xv.w, wd.w, acc.w);
    }
    int row = row0 + trow;
    float di = dinv[row];
    float4 o = {acc.x * di, acc.y * di, acc.z * di, acc.w * di};
    reinterpret_cast<float4*>(g + (size_t)row * 64)[tcol] = o;
  }
}

// --- pull layer 2 (F=64) + both heads fused; h2 never materialized ---
__global__ __launch_bounds__(256) void k_pull2(const float* __restrict__ g,
                                               const int* __restrict__ rs,
                                               const int* __restrict__ cnt,
                                               const int* __restrict__ col,
                                               const float* __restrict__ dinv,
                                               const float* __restrict__ b,
                                               const float* __restrict__ Wd,
                                               const float* __restrict__ Wp,
                                               const float* __restrict__ bd,
                                               const float* __restrict__ bp,
                                               float* __restrict__ out, int n) {
  int node = (blockIdx.x * 256 + threadIdx.x) >> 6;
  int lane = threadIdx.x & 63;
  if (node >= n) return;
  int f4 = (lane & 15) * 4;
  int grp = lane >> 4;
  int start = rs[node], m = cnt[node];
  float4 acc = {0.f, 0.f, 0.f, 0.f};
  for (int base0 = 0; base0 < m; base0 += 64) {
    int lim = min(64, m - base0);
    int idx = (lane < lim) ? col[start + base0 + lane] : 0;
    int nt = lim >> 2;
    int t = 0;
    for (; t + 2 <= nt; t += 2) {
      int e0 = t * 4 + grp, e1 = e0 + 4;
      int s0 = __shfl(idx, e0), s1 = __shfl(idx, e1);
      float4 v0 = *reinterpret_cast<const float4*>(g + (size_t)s0 * 64 + f4);
      float4 v1 = *reinterpret_cast<const float4*>(g + (size_t)s1 * 64 + f4);
      acc.x += v0.x + v1.x; acc.y += v0.y + v1.y;
      acc.z += v0.z + v1.z; acc.w += v0.w + v1.w;
    }
    if (t < nt) {
      int e0 = t * 4 + grp;
      int s0 = __shfl(idx, e0);
      float4 v0 = *reinterpret_cast<const float4*>(g + (size_t)s0 * 64 + f4);
      acc.x += v0.x; acc.y += v0.y; acc.z += v0.z; acc.w += v0.w;
    }
    for (int j = nt * 4; j < lim; ++j) {
      int s0 = __shfl(idx, j);
      if (grp == (j & 3)) {
        float4 v0 = *reinterpret_cast<const float4*>(g + (size_t)s0 * 64 + f4);
        acc.x += v0.x; acc.y += v0.y; acc.z += v0.z; acc.w += v0.w;
      }
    }
  }
  acc.x += __shfl_xor(acc.x, 16); acc.y += __shfl_xor(acc.y, 16);
  acc.z += __shfl_xor(acc.z, 16); acc.w += __shfl_xor(acc.w, 16);
  acc.x += __shfl_xor(acc.x, 32); acc.y += __shfl_xor(acc.y, 32);
  acc.z += __shfl_xor(acc.z, 32); acc.w += __shfl_xor(acc.w, 32);
  float4 sv = *reinterpret_cast<const float4*>(g + (size_t)node * 64 + f4);
  acc.x += sv.x; acc.y += sv.y; acc.z += sv.z; acc.w += sv.w;
  float di = dinv[node];
  float4 b4 = *reinterpret_cast<const float4*>(b + f4);
  float4 wd4 = *reinterpret_cast<const float4*>(Wd + f4);
  float4 wp4 = *reinterpret_cast<const float4*>(Wp + f4);
  float vx = fmaxf(fmaf(acc.x, di, b4.x), 0.f);
  float vy = fmaxf(fmaf(acc.y, di, b4.y), 0.f);
  float vz = fmaxf(fmaf(acc.z, di, b4.z), 0.f);
  float vw = fmaxf(fmaf(acc.w, di, b4.w), 0.f);
  float dsum = vx * wd4.x + vy * wd4.y + vz * wd4.z + vw * wd4.w;
  float psum = vx * wp4.x + vy * wp4.y + vz * wp4.z + vw * wp4.w;
#pragma unroll
  for (int off = 1; off < 16; off <<= 1) {
    dsum += __shfl_xor(dsum, off);
    psum += __shfl_xor(psum, off);
  }
  if (lane == 0) {
    out[node] = dsum + bd[0];
    out[n + node] = psum + bp[0];
  }
}

extern "C" void kernel_launch(void* const* d_in, const int* in_sizes, int n_in,
                              void* d_out, int out_size, void* d_ws, size_t ws_size,
                              hipStream_t stream) {
  const float* x  = (const float*)d_in[0];
  const int*   ei = (const int*)d_in[1];
  const float* W1 = (const float*)d_in[2];
  const float* b1 = (const float*)d_in[3];
  const float* W2 = (const float*)d_in[4];
  const float* b2 = (const float*)d_in[5];
  const float* Wd = (const float*)d_in[6];
  const float* bd = (const float*)d_in[7];
  const float* Wp = (const float*)d_in[8];
  const float* bp = (const float*)d_in[9];
  float* out = (float*)d_out;

  const int N = in_sizes[0] / 64;
  const int E = in_sizes[1] / 2;
  const int* src = ei;
  const int* dst = ei + E;
  const int nc = (N + 255) >> 8;  // 391 coarse buckets (<= MAXC)

  char* ws = (char*)d_ws;
  size_t off = 0;
  auto alloc = [&](size_t bytes) -> void* {
    size_t a = (off + 255) & ~(size_t)255;
    off = a + bytes;
    return (void*)(ws + a);
  };

  int*   c    = (int*)alloc((size_t)N * 4);
  int*   rs   = (int*)alloc((size_t)N * 4);
  int*   bsum = (int*)alloc(1024);
  float* dinv = (float*)alloc((size_t)N * 4);
  int*   gcur = (int*)alloc((size_t)MAXC * 4);
  int*   P    = (int*)alloc((size_t)E * 4);
  int*   col  = (int*)alloc((size_t)E * 4);
  float* agg  = (float*)alloc((size_t)N * 64 * 4);  // reused as g2 after gemm1
  float* h1   = (float*)alloc((size_t)N * 128 * 4);
  float* g2   = agg;  // agg dead once gemm1 consumed it
  (void)ws_size; (void)n_in; (void)out_size;

  hipMemsetAsync(c, 0, (size_t)N * 4, stream);

  k_deg<<<(E + 255) / 256, 256, 0, stream>>>(dst, c, E);
  k_dinv<<<(N + 255) / 256, 256, 0, stream>>>(c, dinv, N);

  int nb = (N + 1023) / 1024;  // 98 <= 128
  k_scan1<<<nb, 256, 0, stream>>>(c, rs, bsum, N);
  k_scan2<<<1, 128, 0, stream>>>(bsum, nb);
  k_scan3<<<(N + 255) / 256, 256, 0, stream>>>(rs, bsum, N);

  k_binit<<<(nc + 255) / 256, 256, 0, stream>>>(rs, gcur, nc);
  int seg = (E + 511) / 512;
  k_pass1<<<512, 256, 0, stream>>>(src, dst, gcur, P, E, nc, seg);
  k_pass2<<<nc, 256, 0, stream>>>(P, rs, col, N, E);

  k_pull1<<<(N + 3) / 4, 256, 0, stream>>>(x, rs, c, col, dinv, agg, N);
  k_gemm1<<<2048, 256, 0, stream>>>(agg, W1, b1, h1, N);
  k_gemm2<<<2048, 256, 0, stream>>>(h1, W2, dinv, g2, N);
  k_pull2<<<(N + 3) / 4, 256, 0, stream>>>(g2, rs, c, col, dinv, b2, Wd, Wp, bd, bp, out, N);
}